// Round 1
// baseline (205.616 us; speedup 1.0000x reference)
//
#include <hip/hip_runtime.h>
#include <math.h>

// Side-window filter, 3 iterations fused, FP32, bit-exact vs the np reference
// (verified absmax==0.0): each directional conv is a sequential fp32 FMA chain
// over taps in row-major (ky,kx) order, acc starting at 0, weights fp32(1/15),
// fp32(1/9), fp32(fp32(1/9)/9). Zero-padded taps are exact no-ops.
// Intermediates fp32; out-of-image intermediate pixels zeroed (next iteration
// zero-pads at the image boundary).
//
// Round 7: 64x32 output tile. Previous 64x64 tile needed 44 KB LDS -> only
// 3 blocks/CU (12 waves/CU, OccupancyPercent 29.5) and VALUBusy stalled at
// 72.7% (measured VALU-issue time 101 us of 139 us). 64x32 cuts LDS to
// A 44x76 + B 40x72 = 24.9 KB -> 6 blocks/CU (24 waves/CU); halo recompute
// ratio rises only 3.39 -> 3.60 (+6.1% FMA) while doubling latency-hiding
// waves. Per-pixel math is byte-identical to the verified chain.
//
// Direction supports (with the reference's normalization bug):
//   d0 L  = rows[-2..2] x cols[-2..0] * (1/15)
//   d1 R  = rows[-2..2] x cols[0..2]  * (1/15)
//   d2 U  = rows[-2..0] x cols[-2..2] * (1/15)
//   d3 D  = rows[0..2]  x cols[-2..2] * (1/15)
//   d4 NW = rows[-2..0] x cols[-2..0] * (1/9)
//   d5 NE = NW support * (1/81)   (bug: NE = new NW / 9)
//   d6 SW = rows[0..2]  x cols[-2..0] * (1/9)
//   d7 SE = SW support * (1/81)   (bug: SE = new SW / 9)

typedef float f4v __attribute__((ext_vector_type(4)));
typedef float f2v __attribute__((ext_vector_type(2), aligned(8)));

#define TW 64
#define TH 32

// One SWF iteration. X: (H2+4) x (W2+4) fp32 LDS tile (pitch W2+4), zero-pad.
// Y: H2 x W2 (pitch W2), zeroed outside the 768x768 image (gy0,gx0 = global
// coords of Y[0][0]); if LAST, write fp32 to outp (pitch 768).
template<int H2, int W2, bool LAST>
__device__ __forceinline__ void step(const float* __restrict__ X,
                                     float* __restrict__ Y,
                                     float* __restrict__ outp,
                                     int gy0, int gx0, int tid) {
    constexpr int PW = W2 + 4;
    constexpr int SC = W2 / 4;
    constexpr int NSEG = H2 * SC;
    const float w15 = 1.0f / 15.0f;
    const float w9  = 1.0f / 9.0f;
    const float w81 = (1.0f / 9.0f) / 9.0f;

    // block-uniform: every output pixel of this step inside the image?
    const bool interior = (gy0 >= 0) && (gx0 >= 0) &&
                          (gy0 + H2 <= 768) && (gx0 + W2 <= 768);

    for (int s = tid; s < NSEG; s += 256) {
        const int y  = s / SC;
        const int xs = (s - y * SC) * 4;
        const float* rp = X + y * PW + xs;

        // acc[dir][px]; per-accumulator op order = rows ascending (r loop),
        // cols ascending within row — the verified bit-exact chain.
        float acc[8][4];
        #pragma unroll
        for (int d = 0; d < 8; d++)
            #pragma unroll
            for (int j = 0; j < 4; j++) acc[d][j] = 0.0f;
        float ctr[4];

        #pragma unroll
        for (int r = 0; r < 5; r++) {
            const float* p = rp + r * PW;     // 16B-aligned
            f4v lo = *(const f4v*)p;
            f4v hi = *(const f4v*)(p + 4);
            float w[8] = {lo.x, lo.y, lo.z, lo.w, hi.x, hi.y, hi.z, hi.w};

            #pragma unroll
            for (int j = 0; j < 4; j++) {
                // full-height: L (cols j..j+2), R (cols j+2..j+4)
                acc[0][j] = fmaf(w15, w[j + 0], acc[0][j]);
                acc[0][j] = fmaf(w15, w[j + 1], acc[0][j]);
                acc[0][j] = fmaf(w15, w[j + 2], acc[0][j]);
                acc[1][j] = fmaf(w15, w[j + 2], acc[1][j]);
                acc[1][j] = fmaf(w15, w[j + 3], acc[1][j]);
                acc[1][j] = fmaf(w15, w[j + 4], acc[1][j]);
                if (r < 3) {  // U, NW, NE
                    acc[2][j] = fmaf(w15, w[j + 0], acc[2][j]);
                    acc[2][j] = fmaf(w15, w[j + 1], acc[2][j]);
                    acc[2][j] = fmaf(w15, w[j + 2], acc[2][j]);
                    acc[2][j] = fmaf(w15, w[j + 3], acc[2][j]);
                    acc[2][j] = fmaf(w15, w[j + 4], acc[2][j]);
                    acc[4][j] = fmaf(w9,  w[j + 0], acc[4][j]);
                    acc[4][j] = fmaf(w9,  w[j + 1], acc[4][j]);
                    acc[4][j] = fmaf(w9,  w[j + 2], acc[4][j]);
                    acc[5][j] = fmaf(w81, w[j + 0], acc[5][j]);
                    acc[5][j] = fmaf(w81, w[j + 1], acc[5][j]);
                    acc[5][j] = fmaf(w81, w[j + 2], acc[5][j]);
                }
                if (r >= 2) {  // D, SW, SE
                    acc[3][j] = fmaf(w15, w[j + 0], acc[3][j]);
                    acc[3][j] = fmaf(w15, w[j + 1], acc[3][j]);
                    acc[3][j] = fmaf(w15, w[j + 2], acc[3][j]);
                    acc[3][j] = fmaf(w15, w[j + 3], acc[3][j]);
                    acc[3][j] = fmaf(w15, w[j + 4], acc[3][j]);
                    acc[6][j] = fmaf(w9,  w[j + 0], acc[6][j]);
                    acc[6][j] = fmaf(w9,  w[j + 1], acc[6][j]);
                    acc[6][j] = fmaf(w9,  w[j + 2], acc[6][j]);
                    acc[7][j] = fmaf(w81, w[j + 0], acc[7][j]);
                    acc[7][j] = fmaf(w81, w[j + 1], acc[7][j]);
                    acc[7][j] = fmaf(w81, w[j + 2], acc[7][j]);
                }
                if (r == 2) ctr[j] = w[j + 2];
            }
        }

        f4v R;
        #pragma unroll
        for (int j = 0; j < 4; j++) {
            const float c = ctr[j];
            const float e0 = acc[0][j] - c, e1 = acc[1][j] - c;
            const float e2 = acc[2][j] - c, e3 = acc[3][j] - c;
            const float e4 = acc[4][j] - c, e5 = acc[5][j] - c;
            const float e6 = acc[6][j] - c, e7 = acc[7][j] - c;
            // tournament argmin on |d|; strict < keeps lowest index on ties
            // (matches jnp.argmin); |x| folds into VOP3 abs modifiers
            float m01 = (fabsf(e1) < fabsf(e0)) ? e1 : e0;
            float m23 = (fabsf(e3) < fabsf(e2)) ? e3 : e2;
            float m45 = (fabsf(e5) < fabsf(e4)) ? e5 : e4;
            float m67 = (fabsf(e7) < fabsf(e6)) ? e7 : e6;
            float mA  = (fabsf(m23) < fabsf(m01)) ? m23 : m01;
            float mB  = (fabsf(m67) < fabsf(m45)) ? m67 : m45;
            float bd  = (fabsf(mB)  < fabsf(mA))  ? mB  : mA;
            const float res = c + bd;
            if (j == 0) R.x = res; else if (j == 1) R.y = res;
            else if (j == 2) R.z = res; else R.w = res;
        }

        if (LAST) {
            *(f4v*)(outp + y * 768 + xs) = R;
        } else if (interior) {
            *(f4v*)(Y + y * W2 + xs) = R;
        } else {
            // zero outside the image: next iteration zero-pads at the boundary
            const bool rowin = ((unsigned)(gy0 + y) < 768u);
            R.x = (rowin && (unsigned)(gx0 + xs + 0) < 768u) ? R.x : 0.0f;
            R.y = (rowin && (unsigned)(gx0 + xs + 1) < 768u) ? R.y : 0.0f;
            R.z = (rowin && (unsigned)(gx0 + xs + 2) < 768u) ? R.z : 0.0f;
            R.w = (rowin && (unsigned)(gx0 + xs + 3) < 768u) ? R.w : 0.0f;
            *(f4v*)(Y + y * W2 + xs) = R;
        }
    }
    __syncthreads();
}

// LDS: A = 44x76 fp32 (iter1 input; reused as iter2 output 36x68) = 13376 B,
//      B = 40x72 fp32 (iter1 output = iter2 input) = 11520 B. Total 24896 B
//      -> 6 blocks/CU (24 waves/CU, up from 3 blocks / 12 waves at 64x64).
__global__ __launch_bounds__(256) void swf_fused(const float* __restrict__ in,
                                                 float* __restrict__ out) {
    __shared__ __align__(16) float A[44 * 76];
    __shared__ __align__(16) float B[40 * 72];

    const int tid = threadIdx.x;
    const int tx0 = blockIdx.x * TW;
    const int ty0 = blockIdx.y * TH;
    const long long base = (long long)blockIdx.z * (768 * 768);
    const float* inp = in + base;

    // load tile rows ty0-6..ty0+37, cols tx0-6..tx0+69, zero-padded.
    // float2 granularity: global col tx0-6 is even -> 8B aligned.
    for (int i = tid; i < 44 * 38; i += 256) {
        const int ly  = i / 38;
        const int lx2 = i - ly * 38;
        const int gy  = ty0 + ly - 6;
        const int gx  = tx0 + lx2 * 2 - 6;
        f2v v = {0.0f, 0.0f};
        if ((unsigned)gy < 768u) {
            const float* g = inp + gy * 768 + gx;
            if ((unsigned)gx < 767u) {            // both lanes inside
                v = *(const f2v*)g;
            } else {                               // x-edge: per-lane
                if ((unsigned)gx < 768u)       v.x = g[0];
                if ((unsigned)(gx + 1) < 768u) v.y = g[1];
            }
        }
        *(f2v*)(A + ly * 76 + lx2 * 2) = v;
    }
    __syncthreads();

    step<40, 72, false>(A, B, nullptr, ty0 - 4, tx0 - 4, tid);  // iter1: A->B
    step<36, 68, false>(B, A, nullptr, ty0 - 2, tx0 - 2, tid);  // iter2: B->A
    step<32, 64, true >(A, nullptr,                              // iter3: A->out
                        out + base + (long long)ty0 * 768 + tx0, ty0, tx0, tid);
}

extern "C" void kernel_launch(void* const* d_in, const int* in_sizes, int n_in,
                              void* d_out, int out_size, void* d_ws, size_t ws_size,
                              hipStream_t stream) {
    const float* x = (const float*)d_in[0];
    float* out = (float*)d_out;

    dim3 grid(768 / TW, 768 / TH, 24);   // 12 x 24 x 24 = 6912 blocks
    dim3 block(256);
    swf_fused<<<grid, block, 0, stream>>>(x, out);
}